// Round 4
// baseline (9188.349 us; speedup 1.0000x reference)
//
#include <hip/hip_runtime.h>
#include <math.h>

#define DEV static __device__ __forceinline__

typedef short s8v  __attribute__((ext_vector_type(8)));   // 8 bf16 (A/B frag)
typedef short s4v  __attribute__((ext_vector_type(4)));
typedef float f4v  __attribute__((ext_vector_type(4)));   // C/D frag

// round-to-nearest-even f32 -> bf16 (bits in a short)
DEV short bf16rne(float f) {
    unsigned u = __float_as_uint(f);
    unsigned r = (u + 0x7fffu + ((u >> 16) & 1u)) >> 16;
    return (short)r;
}

// Exact-IEEE squared distance, same op order as the numpy/XLA reference.
DEV float sqd(float ax, float ay, float az, float bx, float by, float bz) {
    float dx = __fsub_rn(ax, bx), dy = __fsub_rn(ay, by), dz = __fsub_rn(az, bz);
    return __fadd_rn(__fadd_rn(__fmul_rn(dx, dx), __fmul_rn(dy, dy)), __fmul_rn(dz, dz));
}

// ---------------------------------------------------------------------------
// Radius top-k, one WAVE per query (unchanged from round 3).
// ---------------------------------------------------------------------------
template <int N>
__global__ __launch_bounds__(256) void radius_topk_kernel(
        const float* __restrict__ pos, float rr, int* __restrict__ idx_out) {
    constexpr int Q = N / 64;
    constexpr unsigned long long INV = ~0ull;
    int b = blockIdx.x;
    int wid = threadIdx.x >> 6, lane = threadIdx.x & 63;
    int i = blockIdx.y * 4 + wid;
    const float* p = pos + (size_t)b * N * 3;
    float qx = p[i * 3 + 0], qy = p[i * 3 + 1], qz = p[i * 3 + 2];

    unsigned long long c[Q];
#pragma unroll
    for (int q = 0; q < Q; q++) {
        int jj = q * 64 + lane;
        float px = p[jj * 3 + 0], py = p[jj * 3 + 1], pz = p[jj * 3 + 2];
        float d2 = sqd(px, py, pz, qx, qy, qz);
        bool valid = (jj != i) && (d2 <= rr);
        c[q] = valid ? ((((unsigned long long)__float_as_uint(d2)) << 32)
                        | (unsigned)jj)
                     : INV;
    }

#pragma unroll
    for (int k = 2; k <= Q; k <<= 1) {
#pragma unroll
        for (int jj = k >> 1; jj > 0; jj >>= 1) {
#pragma unroll
            for (int t = 0; t < Q; t++) {
                int l = t ^ jj;
                if (l > t) {
                    bool up = ((t & k) == 0);
                    unsigned long long a = c[t], d = c[l];
                    bool sw = (a > d) != up;
                    c[t] = sw ? d : a;
                    c[l] = sw ? a : d;
                }
            }
        }
    }

    int* orow = idx_out + ((size_t)b * N + i) * 33;
    int cnt = 0;
    for (int s = 0; s < 32; s++) {
        unsigned long long h = c[0];
        unsigned long long g = h;
#pragma unroll
        for (int off = 1; off < 64; off <<= 1) {
            unsigned long long o = __shfl_xor(g, off, 64);
            g = (o < g) ? o : g;
        }
        if (lane == 0) orow[s] = (int)(unsigned)(g & 0xffffffffull);
        cnt += (g != INV) ? 1 : 0;
        if (h == g && g != INV) {
#pragma unroll
            for (int q = 0; q < Q - 1; q++) c[q] = c[q + 1];
            c[Q - 1] = INV;
        }
    }
    if (lane == 0) {
        if (cnt < 32) orow[cnt] = i;
        orow[32] = (cnt == 32) ? i : -1;
    }
}

// ---------------------------------------------------------------------------
// Weight pre-pack (unchanged).
// ---------------------------------------------------------------------------
__global__ void pack_w_kernel(const float* __restrict__ W, short* __restrict__ out,
                              int Kreal, int C, int KS, int total) {
    int t = blockIdx.x * 256 + threadIdx.x;
    if (t >= total) return;
    int lane = t & 63;
    int mk = t >> 6;
    int ks = mk % KS, mt = mk / KS;
    int c = 16 * mt + (lane & 15);
    int k0 = 32 * ks + ((lane >> 4) << 3);
    s8v v;
#pragma unroll
    for (int j = 0; j < 8; j++) {
        int k = k0 + j;
        v[j] = (k < Kreal) ? bf16rne(W[(size_t)k * C + c]) : (short)0;
    }
    *(s8v*)(out + (size_t)t * 8) = v;
}

// ---------------------------------------------------------------------------
// Fused MFMA point-conv (unchanged).
// ---------------------------------------------------------------------------
template <int CXIN, int CH, int PPB, int N>
__global__ __launch_bounds__(256) void conv_mfma_kernel(
        const float* __restrict__ pos, const float* __restrict__ xin,
        const int* __restrict__ idx,
        const short* __restrict__ Wpa, const float* __restrict__ ba,
        const short* __restrict__ Wpb, const float* __restrict__ bb,
        float* __restrict__ xout) {
    constexpr int CIN  = CXIN + 3;
    constexpr int CINp = (CIN + 31) & ~31;
    constexpr int KS1  = CINp / 32, KS2 = CH / 32;
    constexpr int MT   = CH / 16;
    constexpr int MTW  = (PPB == 4) ? MT : MT / 4;
    constexpr int RP   = 48;
    constexpr int NT   = 3;
    constexpr int FS   = CINp * 2 + 16;
    constexpr int HS   = CH * 2 + 16;
    __shared__ __align__(16) char Fs[PPB * RP * FS];
    __shared__ __align__(16) char Hs[PPB * RP * HS];
    __shared__ int sj[PPB * RP];

    int tid = threadIdx.x;
    int lane = tid & 63, wid = tid >> 6;
    int pid0 = blockIdx.x * PPB;

    for (int r = tid; r < PPB * RP; r += 256) {
        int p = r / RP, s = r - p * RP;
        sj[r] = (s < 33) ? idx[(size_t)(pid0 + p) * 33 + s] : -1;
    }
    __syncthreads();

    constexpr int FE = PPB * RP * CINp;
    for (int e = tid; e < FE; e += 256) {
        int r = e / CINp, f = e - r * CINp;
        int p = r / RP;
        int pid = pid0 + p;
        int b = pid / N, i = pid - b * N;
        int j = sj[r];
        float v = 0.f;
        if (j >= 0 && f < CIN) {
            if (f < CXIN) {
                v = xin[((size_t)b * N + j) * CXIN + f];
            } else {
                int a = f - CXIN;
                v = __fsub_rn(pos[((size_t)b * N + j) * 3 + a],
                              pos[((size_t)b * N + i) * 3 + a]);
            }
        }
        *(short*)(Fs + (size_t)r * FS + f * 2) = bf16rne(v);
    }
    __syncthreads();

    int pw  = (PPB == 4) ? wid : 0;
    int mt0 = (PPB == 4) ? 0 : wid * MTW;
    const char* Fw = Fs + pw * RP * FS;
    char* Hw = Hs + pw * RP * HS;
    int lr = lane & 15, lg = lane >> 4;

    f4v acc[MTW][NT];
#pragma unroll
    for (int m = 0; m < MTW; m++)
#pragma unroll
        for (int nt = 0; nt < NT; nt++)
#pragma unroll
            for (int q = 0; q < 4; q++) acc[m][nt][q] = 0.f;
#pragma unroll
    for (int ks = 0; ks < KS1; ks++) {
        s8v bfr[NT];
#pragma unroll
        for (int nt = 0; nt < NT; nt++)
            bfr[nt] = *(const s8v*)(Fw + (nt * 16 + lr) * FS + (32 * ks + lg * 8) * 2);
#pragma unroll
        for (int m = 0; m < MTW; m++) {
            s8v afr = *(const s8v*)(Wpa + (((size_t)(mt0 + m) * KS1 + ks) * 64 + lane) * 8);
#pragma unroll
            for (int nt = 0; nt < NT; nt++)
                acc[m][nt] = __builtin_amdgcn_mfma_f32_16x16x32_bf16(afr, bfr[nt], acc[m][nt], 0, 0, 0);
        }
    }
#pragma unroll
    for (int m = 0; m < MTW; m++) {
        int cbase = (mt0 + m) * 16 + lg * 4;
        f4v bv = *(const f4v*)(ba + cbase);
#pragma unroll
        for (int nt = 0; nt < NT; nt++) {
            s4v hq;
#pragma unroll
            for (int q = 0; q < 4; q++)
                hq[q] = bf16rne(fmaxf(acc[m][nt][q] + bv[q], 0.f));
            *(s4v*)(Hw + (nt * 16 + lr) * HS + cbase * 2) = hq;
        }
    }
    __syncthreads();

    f4v acc2[MTW][NT];
#pragma unroll
    for (int m = 0; m < MTW; m++)
#pragma unroll
        for (int nt = 0; nt < NT; nt++)
#pragma unroll
            for (int q = 0; q < 4; q++) acc2[m][nt][q] = 0.f;
#pragma unroll
    for (int ks = 0; ks < KS2; ks++) {
        s8v bfr[NT];
#pragma unroll
        for (int nt = 0; nt < NT; nt++)
            bfr[nt] = *(const s8v*)(Hw + (nt * 16 + lr) * HS + (32 * ks + lg * 8) * 2);
#pragma unroll
        for (int m = 0; m < MTW; m++) {
            s8v afr = *(const s8v*)(Wpb + (((size_t)(mt0 + m) * KS2 + ks) * 64 + lane) * 8);
#pragma unroll
            for (int nt = 0; nt < NT; nt++)
                acc2[m][nt] = __builtin_amdgcn_mfma_f32_16x16x32_bf16(afr, bfr[nt], acc2[m][nt], 0, 0, 0);
        }
    }

    const int* sjw = sj + pw * RP;
#pragma unroll
    for (int m = 0; m < MTW; m++) {
        int cbase = (mt0 + m) * 16 + lg * 4;
        f4v bv = *(const f4v*)(bb + cbase);
        f4v vmx;
#pragma unroll
        for (int q = 0; q < 4; q++) vmx[q] = 0.f;
#pragma unroll
        for (int nt = 0; nt < NT; nt++) {
            int s = nt * 16 + lr;
            bool valid = (s < 33) && (sjw[s] >= 0);
#pragma unroll
            for (int q = 0; q < 4; q++) {
                float v = fmaxf(acc2[m][nt][q] + bv[q], 0.f);
                if (valid) vmx[q] = fmaxf(vmx[q], v);
            }
        }
#pragma unroll
        for (int off = 1; off < 16; off <<= 1)
#pragma unroll
            for (int q = 0; q < 4; q++)
                vmx[q] = fmaxf(vmx[q], __shfl_xor(vmx[q], off, 64));
        if (lr == 0) {
            int pid = pid0 + pw;
            *(f4v*)(xout + (size_t)pid * CH + cbase) = vmx;
        }
    }
}

// ---------------------------------------------------------------------------
// Wave-synchronous FPS: one 64-lane wave per cloud, no barriers in the loop.
// Lane owns 2*PAIRS points (coords + running d in registers, static indices).
// Per iter: in-register argmax tree (ascending-j layout => strict > keeps
// lowest index, matching jnp.argmax), u64 key (d2_bits<<32)|(~j) wave-max via
// shfl_xor (tie -> lowest j), uniform LDS b128 read of winner coords, exact
// IEEE d-update (no FMA contraction).
// ---------------------------------------------------------------------------
template <int N, int M>
__global__ __launch_bounds__(64, 1) void fps_wave_kernel(
        const float* __restrict__ pos, int* __restrict__ s_out) {
    constexpr int PTS = N / 64;           // points per lane (power of 2)
    __shared__ float sp[N][4];            // padded for aligned b128 broadcast
    int b = blockIdx.x;
    const float* p = pos + (size_t)b * N * 3;
    int lane = threadIdx.x;

    // stage positions (for the per-iteration uniform winner-coord read)
    for (int j = lane; j < N; j += 64) {
        sp[j][0] = p[j * 3 + 0];
        sp[j][1] = p[j * 3 + 1];
        sp[j][2] = p[j * 3 + 2];
        sp[j][3] = 0.f;
    }
    __syncthreads();

    // register-resident coords + distances; j(t) = 128*(t>>1) + 2*lane + (t&1)
    float cx[PTS], cy[PTS], cz[PTS], d[PTS];
    float x0 = sp[0][0], y0 = sp[0][1], z0 = sp[0][2];
#pragma unroll
    for (int t = 0; t < PTS; t++) {
        int j = 128 * (t >> 1) + 2 * lane + (t & 1);
        cx[t] = p[j * 3 + 0];
        cy[t] = p[j * 3 + 1];
        cz[t] = p[j * 3 + 2];
        d[t] = sqd(cx[t], cy[t], cz[t], x0, y0, z0);
    }

    int* so = s_out + b * M;
    if (lane == 0) so[0] = 0;

    for (int m = 1; m < M; m++) {
        // per-lane argmax tree (j(t) monotone in t => strict > keeps lowest j)
        float v[PTS];
        unsigned ji[PTS];
#pragma unroll
        for (int t = 0; t < PTS; t++) {
            v[t] = d[t];
            ji[t] = (unsigned)(128 * (t >> 1) + 2 * lane + (t & 1));
        }
#pragma unroll
        for (int s = PTS / 2; s >= 1; s >>= 1) {
#pragma unroll
            for (int t = 0; t < s; t++) {
                bool take = (v[t + s] > v[t]);
                v[t] = take ? v[t + s] : v[t];
                ji[t] = take ? ji[t + s] : ji[t];
            }
        }
        // wave max of (d2, ~j): d asc bits (d>=0), tie -> lowest j
        unsigned long long key =
            (((unsigned long long)__float_as_uint(v[0])) << 32)
            | (unsigned)(0xFFFFFFFFu - ji[0]);
#pragma unroll
        for (int off = 1; off < 64; off <<= 1) {
            unsigned long long o = __shfl_xor(key, off, 64);
            key = (o > key) ? o : key;
        }
        unsigned jwin = 0xFFFFFFFFu - (unsigned)(key & 0xFFFFFFFFull);
        if (lane == 0) so[m] = (int)jwin;

        const f4v sel = *(const f4v*)&sp[jwin][0];   // uniform broadcast read
#pragma unroll
        for (int t = 0; t < PTS; t++) {
            float di = sqd(cx[t], cy[t], cz[t], sel[0], sel[1], sel[2]);
            d[t] = fminf(d[t], di);
        }
    }
}

// ---------------------------------------------------------------------------
__global__ void gather_kernel(
        const float* __restrict__ pos_in, const float* __restrict__ x_in,
        const int* __restrict__ s, int Nin, int M, int C,
        float* __restrict__ pos_out, float* __restrict__ x_out) {
    int b = blockIdx.y, m = blockIdx.x, t = threadIdx.x;
    int j = s[b * M + m];
    x_out[((size_t)b * M + m) * C + t] = x_in[((size_t)b * Nin + j) * C + t];
    if (t < 3) pos_out[((size_t)b * M + m) * 3 + t] = pos_in[((size_t)b * Nin + j) * 3 + t];
}

// ---------------------------------------------------------------------------
// Global max pool + MLP head + log_softmax (unchanged).
// ---------------------------------------------------------------------------
__global__ __launch_bounds__(256) void head_kernel(
        const float* __restrict__ x3,
        const float* __restrict__ Wl1, const float* __restrict__ bl1,
        const float* __restrict__ Wl2, const float* __restrict__ bl2,
        const float* __restrict__ Wl3, const float* __restrict__ bl3,
        float* __restrict__ out) {
    __shared__ float gbuf[256], h1[256], h2[256], h3[40];
    int b = blockIdx.x, c = threadIdx.x;
    const float* xb = x3 + (size_t)b * 256 * 256;
    float m = -INFINITY;
    for (int r = 0; r < 256; r++) m = fmaxf(m, xb[r * 256 + c]);
    gbuf[c] = m;
    __syncthreads();
    float a = bl1[c];
    for (int k = 0; k < 256; k++) a = fmaf(gbuf[k], Wl1[k * 256 + c], a);
    h1[c] = fmaxf(a, 0.f);
    __syncthreads();
    a = bl2[c];
    for (int k = 0; k < 256; k++) a = fmaf(h1[k], Wl2[k * 256 + c], a);
    h2[c] = fmaxf(a, 0.f);
    __syncthreads();
    if (c < 40) {
        a = bl3[c];
        for (int k = 0; k < 256; k++) a = fmaf(h2[k], Wl3[k * 40 + c], a);
        h3[c] = a;
    }
    __syncthreads();
    if (c < 64) {
        float v = -INFINITY;
        if (c < 40) v = h3[c];
        float mx = v;
#pragma unroll
        for (int off = 32; off >= 1; off >>= 1) mx = fmaxf(mx, __shfl_xor(mx, off, 64));
        float e = (c < 40) ? expf(__fsub_rn(v, mx)) : 0.f;
        float s = e;
#pragma unroll
        for (int off = 32; off >= 1; off >>= 1) s = __fadd_rn(s, __shfl_xor(s, off, 64));
        float ls = logf(s);
        if (c < 40) out[b * 40 + c] = __fsub_rn(__fsub_rn(v, mx), ls);
    }
}

// ---------------------------------------------------------------------------
extern "C" void kernel_launch(void* const* d_in, const int* in_sizes, int n_in,
                              void* d_out, int out_size, void* d_ws, size_t ws_size,
                              hipStream_t stream) {
    (void)in_sizes; (void)n_in; (void)out_size; (void)ws_size;
    const float* pos = (const float*)d_in[0];
    const float* W1a = (const float*)d_in[2];
    const float* b1a = (const float*)d_in[3];
    const float* W1b = (const float*)d_in[4];
    const float* b1b = (const float*)d_in[5];
    const float* W2a = (const float*)d_in[6];
    const float* b2a = (const float*)d_in[7];
    const float* W2b = (const float*)d_in[8];
    const float* b2b = (const float*)d_in[9];
    const float* W3a = (const float*)d_in[10];
    const float* b3a = (const float*)d_in[11];
    const float* W3b = (const float*)d_in[12];
    const float* b3b = (const float*)d_in[13];
    const float* Wl1 = (const float*)d_in[14];
    const float* bl1 = (const float*)d_in[15];
    const float* Wl2 = (const float*)d_in[16];
    const float* bl2 = (const float*)d_in[17];
    const float* Wl3 = (const float*)d_in[18];
    const float* bl3 = (const float*)d_in[19];
    float* out = (float*)d_out;

    const int B = 32;
    char* w = (char*)d_ws;
    auto alloc = [&](size_t bytes) -> char* {
        char* r = w;
        w += (bytes + 255) & ~(size_t)255;
        return r;
    };
    int*   idx1 = (int*)  alloc((size_t)B * 2048 * 33 * 4);
    float* x1   = (float*)alloc((size_t)B * 2048 * 64 * 4);
    int*   s1   = (int*)  alloc((size_t)B * 1024 * 4);
    float* pos2 = (float*)alloc((size_t)B * 1024 * 3 * 4);
    float* x2in = (float*)alloc((size_t)B * 1024 * 64 * 4);
    int*   idx2 = (int*)  alloc((size_t)B * 1024 * 33 * 4);
    float* x2   = (float*)alloc((size_t)B * 1024 * 128 * 4);
    int*   s2   = (int*)  alloc((size_t)B * 256 * 4);
    float* pos3 = (float*)alloc((size_t)B * 256 * 3 * 4);
    float* x3in = (float*)alloc((size_t)B * 256 * 128 * 4);
    int*   idx3 = (int*)  alloc((size_t)B * 256 * 33 * 4);
    float* x3   = (float*)alloc((size_t)B * 256 * 256 * 4);
    short* Wp1a = (short*)alloc(4  * 1 * 64 * 8 * 2);
    short* Wp1b = (short*)alloc(4  * 2 * 64 * 8 * 2);
    short* Wp2a = (short*)alloc(8  * 3 * 64 * 8 * 2);
    short* Wp2b = (short*)alloc(8  * 4 * 64 * 8 * 2);
    short* Wp3a = (short*)alloc(16 * 5 * 64 * 8 * 2);
    short* Wp3b = (short*)alloc(16 * 8 * 64 * 8 * 2);

    pack_w_kernel<<<1,  256, 0, stream>>>(W1a, Wp1a, 3,   64,  1, 256);
    pack_w_kernel<<<2,  256, 0, stream>>>(W1b, Wp1b, 64,  64,  2, 512);
    pack_w_kernel<<<6,  256, 0, stream>>>(W2a, Wp2a, 67,  128, 3, 1536);
    pack_w_kernel<<<8,  256, 0, stream>>>(W2b, Wp2b, 128, 128, 4, 2048);
    pack_w_kernel<<<20, 256, 0, stream>>>(W3a, Wp3a, 131, 256, 5, 5120);
    pack_w_kernel<<<32, 256, 0, stream>>>(W3b, Wp3b, 256, 256, 8, 8192);

    // ---- SA module 1 (2048 pts, r=0.2) ----
    radius_topk_kernel<2048><<<dim3(B, 512), 256, 0, stream>>>(pos, 0.04f, idx1);
    conv_mfma_kernel<0, 64, 4, 2048><<<B * 2048 / 4, 256, 0, stream>>>(
        pos, nullptr, idx1, Wp1a, b1a, Wp1b, b1b, x1);
    fps_wave_kernel<2048, 1024><<<B, 64, 0, stream>>>(pos, s1);
    gather_kernel<<<dim3(1024, B), 64, 0, stream>>>(pos, x1, s1, 2048, 1024, 64, pos2, x2in);

    // ---- SA module 2 (1024 pts, r=0.4) ----
    radius_topk_kernel<1024><<<dim3(B, 256), 256, 0, stream>>>(pos2, 0.16f, idx2);
    conv_mfma_kernel<64, 128, 1, 1024><<<B * 1024, 256, 0, stream>>>(
        pos2, x2in, idx2, Wp2a, b2a, Wp2b, b2b, x2);
    fps_wave_kernel<1024, 256><<<B, 64, 0, stream>>>(pos2, s2);
    gather_kernel<<<dim3(256, B), 128, 0, stream>>>(pos2, x2, s2, 1024, 256, 128, pos3, x3in);

    // ---- SA module 3 (256 pts, r=1.0) ----
    radius_topk_kernel<256><<<dim3(B, 64), 256, 0, stream>>>(pos3, 1.0f, idx3);
    conv_mfma_kernel<128, 256, 1, 256><<<B * 256, 256, 0, stream>>>(
        pos3, x3in, idx3, Wp3a, b3a, Wp3b, b3b, x3);

    // ---- global pool + head ----
    head_kernel<<<B, 256, 0, stream>>>(x3, Wl1, bl1, Wl2, bl2, Wl3, bl3, out);
}

// Round 5
// 3033.811 us; speedup vs baseline: 3.0286x; 3.0286x over previous
//
#include <hip/hip_runtime.h>
#include <math.h>

#define DEV static __device__ __forceinline__

typedef short s8v  __attribute__((ext_vector_type(8)));   // 8 bf16 (A/B frag)
typedef short s4v  __attribute__((ext_vector_type(4)));
typedef float f4v  __attribute__((ext_vector_type(4)));   // C/D frag

// round-to-nearest-even f32 -> bf16 (bits in a short)
DEV short bf16rne(float f) {
    unsigned u = __float_as_uint(f);
    unsigned r = (u + 0x7fffu + ((u >> 16) & 1u)) >> 16;
    return (short)r;
}

// Exact-IEEE squared distance, same op order as the numpy/XLA reference.
DEV float sqd(float ax, float ay, float az, float bx, float by, float bz) {
    float dx = __fsub_rn(ax, bx), dy = __fsub_rn(ay, by), dz = __fsub_rn(az, bz);
    return __fadd_rn(__fadd_rn(__fmul_rn(dx, dx), __fmul_rn(dy, dy)), __fmul_rn(dz, dz));
}

// ---------------------------------------------------------------------------
// Fused radius top-k + FPS. blockIdx.y < N/4: radius waves (one wave/query).
// blockIdx.y == N/4: one wave runs the whole cloud's FPS chain concurrently
// with the radius blocks (both only read pos).
//
// FPS design notes (round-4 post-mortem): keep ONLY d[N/64] in registers
// (<=32 floats; round-4's 224-reg coord arrays spilled to scratch, 32x
// regression). Coords live in LDS float4 rows, re-read per iteration via an
// LICM-opaque zero index so the compiler cannot hoist them back into
// registers. Argmax is fused into the d-update pass (no index-tree arrays).
// Selection math exact-IEEE fp32; argmax ties -> lowest j (jnp semantics).
// ---------------------------------------------------------------------------
template <int N, int M>
__global__ __launch_bounds__(256) void radius_fps_kernel(
        const float* __restrict__ pos, float rr, int* __restrict__ idx_out,
        int* __restrict__ s_out) {
    __shared__ __align__(16) float sp4[N][4];
    int b = blockIdx.x;
    const float* p = pos + (size_t)b * N * 3;

    if (blockIdx.y == N / 4) {
        // ---------------- FPS path: single wave, no barriers ----------------
        if (threadIdx.x >= 64) return;
        constexpr int PTS = N / 64;
        int lane = threadIdx.x;
        for (int j = lane; j < N; j += 64) {
            sp4[j][0] = p[j * 3 + 0];
            sp4[j][1] = p[j * 3 + 1];
            sp4[j][2] = p[j * 3 + 2];
            sp4[j][3] = 0.f;
        }
        // single wave: ds ordering via lgkmcnt, no barrier needed
        float d[PTS];
#pragma unroll
        for (int t = 0; t < PTS; t++) d[t] = INFINITY;
        float sx = p[0], sy = p[1], sz = p[2];
        int* so = s_out + b * M;
        if (lane == 0) so[0] = 0;
#pragma unroll 1
        for (int m = 1; m < M; m++) {
            unsigned zero = 0;
            asm volatile("" : "+v"(zero));   // defeat LICM on LDS coord reads
            float best = -INFINITY;
            int bj = 0;
#pragma unroll
            for (int t = 0; t < PTS; t++) {
                int j = t * 64 + lane;
                f4v c = *(const f4v*)&sp4[zero + j][0];
                float di = sqd(c[0], c[1], c[2], sx, sy, sz);
                float dn = fminf(d[t], di);
                d[t] = dn;
                bool take = dn > best;      // strict >: first max kept (j asc in t)
                best = take ? dn : best;
                bj = take ? j : bj;
            }
            // wave argmax of (d, tie -> lowest j): u64 key max
            unsigned long long key =
                (((unsigned long long)__float_as_uint(best)) << 32)
                | (unsigned)(0xFFFFFFFFu - (unsigned)bj);
#pragma unroll
            for (int off = 1; off < 64; off <<= 1) {
                unsigned long long o = __shfl_xor(key, off, 64);
                key = (o > key) ? o : key;
            }
            unsigned jwin = 0xFFFFFFFFu - (unsigned)(key & 0xFFFFFFFFull);
            if (lane == 0) so[m] = (int)jwin;
            f4v sel = *(const f4v*)&sp4[jwin][0];
            sx = sel[0]; sy = sel[1]; sz = sel[2];
        }
        return;
    }

    // ---------------- radius top-k path: one wave per query ----------------
    constexpr int Q = N / 64;
    constexpr unsigned long long INV = ~0ull;
    int wid = threadIdx.x >> 6, lane = threadIdx.x & 63;
    int i = blockIdx.y * 4 + wid;
    float qx = p[i * 3 + 0], qy = p[i * 3 + 1], qz = p[i * 3 + 2];

    unsigned long long c[Q];
#pragma unroll
    for (int q = 0; q < Q; q++) {
        int jj = q * 64 + lane;
        float px = p[jj * 3 + 0], py = p[jj * 3 + 1], pz = p[jj * 3 + 2];
        float d2 = sqd(px, py, pz, qx, qy, qz);
        bool valid = (jj != i) && (d2 <= rr);
        c[q] = valid ? ((((unsigned long long)__float_as_uint(d2)) << 32)
                        | (unsigned)jj)
                     : INV;
    }

#pragma unroll
    for (int k = 2; k <= Q; k <<= 1) {
#pragma unroll
        for (int jj = k >> 1; jj > 0; jj >>= 1) {
#pragma unroll
            for (int t = 0; t < Q; t++) {
                int l = t ^ jj;
                if (l > t) {
                    bool up = ((t & k) == 0);
                    unsigned long long a = c[t], d = c[l];
                    bool sw = (a > d) != up;
                    c[t] = sw ? d : a;
                    c[l] = sw ? a : d;
                }
            }
        }
    }

    int* orow = idx_out + ((size_t)b * N + i) * 33;
    int cnt = 0;
    for (int s = 0; s < 32; s++) {
        unsigned long long h = c[0];
        unsigned long long g = h;
#pragma unroll
        for (int off = 1; off < 64; off <<= 1) {
            unsigned long long o = __shfl_xor(g, off, 64);
            g = (o < g) ? o : g;
        }
        if (lane == 0) orow[s] = (int)(unsigned)(g & 0xffffffffull);
        cnt += (g != INV) ? 1 : 0;
        if (h == g && g != INV) {
#pragma unroll
            for (int q = 0; q < Q - 1; q++) c[q] = c[q + 1];
            c[Q - 1] = INV;
        }
    }
    if (lane == 0) {
        if (cnt < 32) orow[cnt] = i;
        orow[32] = (cnt == 32) ? i : -1;
    }
}

// ---------------------------------------------------------------------------
// Plain radius top-k (stage 3, no FPS needed).
// ---------------------------------------------------------------------------
template <int N>
__global__ __launch_bounds__(256) void radius_topk_kernel(
        const float* __restrict__ pos, float rr, int* __restrict__ idx_out) {
    constexpr int Q = N / 64;
    constexpr unsigned long long INV = ~0ull;
    int b = blockIdx.x;
    int wid = threadIdx.x >> 6, lane = threadIdx.x & 63;
    int i = blockIdx.y * 4 + wid;
    const float* p = pos + (size_t)b * N * 3;
    float qx = p[i * 3 + 0], qy = p[i * 3 + 1], qz = p[i * 3 + 2];

    unsigned long long c[Q];
#pragma unroll
    for (int q = 0; q < Q; q++) {
        int jj = q * 64 + lane;
        float px = p[jj * 3 + 0], py = p[jj * 3 + 1], pz = p[jj * 3 + 2];
        float d2 = sqd(px, py, pz, qx, qy, qz);
        bool valid = (jj != i) && (d2 <= rr);
        c[q] = valid ? ((((unsigned long long)__float_as_uint(d2)) << 32)
                        | (unsigned)jj)
                     : INV;
    }

#pragma unroll
    for (int k = 2; k <= Q; k <<= 1) {
#pragma unroll
        for (int jj = k >> 1; jj > 0; jj >>= 1) {
#pragma unroll
            for (int t = 0; t < Q; t++) {
                int l = t ^ jj;
                if (l > t) {
                    bool up = ((t & k) == 0);
                    unsigned long long a = c[t], d = c[l];
                    bool sw = (a > d) != up;
                    c[t] = sw ? d : a;
                    c[l] = sw ? a : d;
                }
            }
        }
    }

    int* orow = idx_out + ((size_t)b * N + i) * 33;
    int cnt = 0;
    for (int s = 0; s < 32; s++) {
        unsigned long long h = c[0];
        unsigned long long g = h;
#pragma unroll
        for (int off = 1; off < 64; off <<= 1) {
            unsigned long long o = __shfl_xor(g, off, 64);
            g = (o < g) ? o : g;
        }
        if (lane == 0) orow[s] = (int)(unsigned)(g & 0xffffffffull);
        cnt += (g != INV) ? 1 : 0;
        if (h == g && g != INV) {
#pragma unroll
            for (int q = 0; q < Q - 1; q++) c[q] = c[q + 1];
            c[Q - 1] = INV;
        }
    }
    if (lane == 0) {
        if (cnt < 32) orow[cnt] = i;
        orow[32] = (cnt == 32) ? i : -1;
    }
}

// ---------------------------------------------------------------------------
// Weight pre-pack (unchanged).
// ---------------------------------------------------------------------------
__global__ void pack_w_kernel(const float* __restrict__ W, short* __restrict__ out,
                              int Kreal, int C, int KS, int total) {
    int t = blockIdx.x * 256 + threadIdx.x;
    if (t >= total) return;
    int lane = t & 63;
    int mk = t >> 6;
    int ks = mk % KS, mt = mk / KS;
    int c = 16 * mt + (lane & 15);
    int k0 = 32 * ks + ((lane >> 4) << 3);
    s8v v;
#pragma unroll
    for (int j = 0; j < 8; j++) {
        int k = k0 + j;
        v[j] = (k < Kreal) ? bf16rne(W[(size_t)k * C + c]) : (short)0;
    }
    *(s8v*)(out + (size_t)t * 8) = v;
}

// ---------------------------------------------------------------------------
// Fused MFMA point-conv (unchanged).
// ---------------------------------------------------------------------------
template <int CXIN, int CH, int PPB, int N>
__global__ __launch_bounds__(256) void conv_mfma_kernel(
        const float* __restrict__ pos, const float* __restrict__ xin,
        const int* __restrict__ idx,
        const short* __restrict__ Wpa, const float* __restrict__ ba,
        const short* __restrict__ Wpb, const float* __restrict__ bb,
        float* __restrict__ xout) {
    constexpr int CIN  = CXIN + 3;
    constexpr int CINp = (CIN + 31) & ~31;
    constexpr int KS1  = CINp / 32, KS2 = CH / 32;
    constexpr int MT   = CH / 16;
    constexpr int MTW  = (PPB == 4) ? MT : MT / 4;
    constexpr int RP   = 48;
    constexpr int NT   = 3;
    constexpr int FS   = CINp * 2 + 16;
    constexpr int HS   = CH * 2 + 16;
    __shared__ __align__(16) char Fs[PPB * RP * FS];
    __shared__ __align__(16) char Hs[PPB * RP * HS];
    __shared__ int sj[PPB * RP];

    int tid = threadIdx.x;
    int lane = tid & 63, wid = tid >> 6;
    int pid0 = blockIdx.x * PPB;

    for (int r = tid; r < PPB * RP; r += 256) {
        int p = r / RP, s = r - p * RP;
        sj[r] = (s < 33) ? idx[(size_t)(pid0 + p) * 33 + s] : -1;
    }
    __syncthreads();

    constexpr int FE = PPB * RP * CINp;
    for (int e = tid; e < FE; e += 256) {
        int r = e / CINp, f = e - r * CINp;
        int p = r / RP;
        int pid = pid0 + p;
        int b = pid / N, i = pid - b * N;
        int j = sj[r];
        float v = 0.f;
        if (j >= 0 && f < CIN) {
            if (f < CXIN) {
                v = xin[((size_t)b * N + j) * CXIN + f];
            } else {
                int a = f - CXIN;
                v = __fsub_rn(pos[((size_t)b * N + j) * 3 + a],
                              pos[((size_t)b * N + i) * 3 + a]);
            }
        }
        *(short*)(Fs + (size_t)r * FS + f * 2) = bf16rne(v);
    }
    __syncthreads();

    int pw  = (PPB == 4) ? wid : 0;
    int mt0 = (PPB == 4) ? 0 : wid * MTW;
    const char* Fw = Fs + pw * RP * FS;
    char* Hw = Hs + pw * RP * HS;
    int lr = lane & 15, lg = lane >> 4;

    f4v acc[MTW][NT];
#pragma unroll
    for (int m = 0; m < MTW; m++)
#pragma unroll
        for (int nt = 0; nt < NT; nt++)
#pragma unroll
            for (int q = 0; q < 4; q++) acc[m][nt][q] = 0.f;
#pragma unroll
    for (int ks = 0; ks < KS1; ks++) {
        s8v bfr[NT];
#pragma unroll
        for (int nt = 0; nt < NT; nt++)
            bfr[nt] = *(const s8v*)(Fw + (nt * 16 + lr) * FS + (32 * ks + lg * 8) * 2);
#pragma unroll
        for (int m = 0; m < MTW; m++) {
            s8v afr = *(const s8v*)(Wpa + (((size_t)(mt0 + m) * KS1 + ks) * 64 + lane) * 8);
#pragma unroll
            for (int nt = 0; nt < NT; nt++)
                acc[m][nt] = __builtin_amdgcn_mfma_f32_16x16x32_bf16(afr, bfr[nt], acc[m][nt], 0, 0, 0);
        }
    }
#pragma unroll
    for (int m = 0; m < MTW; m++) {
        int cbase = (mt0 + m) * 16 + lg * 4;
        f4v bv = *(const f4v*)(ba + cbase);
#pragma unroll
        for (int nt = 0; nt < NT; nt++) {
            s4v hq;
#pragma unroll
            for (int q = 0; q < 4; q++)
                hq[q] = bf16rne(fmaxf(acc[m][nt][q] + bv[q], 0.f));
            *(s4v*)(Hw + (nt * 16 + lr) * HS + cbase * 2) = hq;
        }
    }
    __syncthreads();

    f4v acc2[MTW][NT];
#pragma unroll
    for (int m = 0; m < MTW; m++)
#pragma unroll
        for (int nt = 0; nt < NT; nt++)
#pragma unroll
            for (int q = 0; q < 4; q++) acc2[m][nt][q] = 0.f;
#pragma unroll
    for (int ks = 0; ks < KS2; ks++) {
        s8v bfr[NT];
#pragma unroll
        for (int nt = 0; nt < NT; nt++)
            bfr[nt] = *(const s8v*)(Hw + (nt * 16 + lr) * HS + (32 * ks + lg * 8) * 2);
#pragma unroll
        for (int m = 0; m < MTW; m++) {
            s8v afr = *(const s8v*)(Wpb + (((size_t)(mt0 + m) * KS2 + ks) * 64 + lane) * 8);
#pragma unroll
            for (int nt = 0; nt < NT; nt++)
                acc2[m][nt] = __builtin_amdgcn_mfma_f32_16x16x32_bf16(afr, bfr[nt], acc2[m][nt], 0, 0, 0);
        }
    }

    const int* sjw = sj + pw * RP;
#pragma unroll
    for (int m = 0; m < MTW; m++) {
        int cbase = (mt0 + m) * 16 + lg * 4;
        f4v bv = *(const f4v*)(bb + cbase);
        f4v vmx;
#pragma unroll
        for (int q = 0; q < 4; q++) vmx[q] = 0.f;
#pragma unroll
        for (int nt = 0; nt < NT; nt++) {
            int s = nt * 16 + lr;
            bool valid = (s < 33) && (sjw[s] >= 0);
#pragma unroll
            for (int q = 0; q < 4; q++) {
                float v = fmaxf(acc2[m][nt][q] + bv[q], 0.f);
                if (valid) vmx[q] = fmaxf(vmx[q], v);
            }
        }
#pragma unroll
        for (int off = 1; off < 16; off <<= 1)
#pragma unroll
            for (int q = 0; q < 4; q++)
                vmx[q] = fmaxf(vmx[q], __shfl_xor(vmx[q], off, 64));
        if (lr == 0) {
            int pid = pid0 + pw;
            *(f4v*)(xout + (size_t)pid * CH + cbase) = vmx;
        }
    }
}

// ---------------------------------------------------------------------------
__global__ void gather_kernel(
        const float* __restrict__ pos_in, const float* __restrict__ x_in,
        const int* __restrict__ s, int Nin, int M, int C,
        float* __restrict__ pos_out, float* __restrict__ x_out) {
    int b = blockIdx.y, m = blockIdx.x, t = threadIdx.x;
    int j = s[b * M + m];
    x_out[((size_t)b * M + m) * C + t] = x_in[((size_t)b * Nin + j) * C + t];
    if (t < 3) pos_out[((size_t)b * M + m) * 3 + t] = pos_in[((size_t)b * Nin + j) * 3 + t];
}

// ---------------------------------------------------------------------------
// Global max pool + MLP head + log_softmax (unchanged).
// ---------------------------------------------------------------------------
__global__ __launch_bounds__(256) void head_kernel(
        const float* __restrict__ x3,
        const float* __restrict__ Wl1, const float* __restrict__ bl1,
        const float* __restrict__ Wl2, const float* __restrict__ bl2,
        const float* __restrict__ Wl3, const float* __restrict__ bl3,
        float* __restrict__ out) {
    __shared__ float gbuf[256], h1[256], h2[256], h3[40];
    int b = blockIdx.x, c = threadIdx.x;
    const float* xb = x3 + (size_t)b * 256 * 256;
    float m = -INFINITY;
    for (int r = 0; r < 256; r++) m = fmaxf(m, xb[r * 256 + c]);
    gbuf[c] = m;
    __syncthreads();
    float a = bl1[c];
    for (int k = 0; k < 256; k++) a = fmaf(gbuf[k], Wl1[k * 256 + c], a);
    h1[c] = fmaxf(a, 0.f);
    __syncthreads();
    a = bl2[c];
    for (int k = 0; k < 256; k++) a = fmaf(h1[k], Wl2[k * 256 + c], a);
    h2[c] = fmaxf(a, 0.f);
    __syncthreads();
    if (c < 40) {
        a = bl3[c];
        for (int k = 0; k < 256; k++) a = fmaf(h2[k], Wl3[k * 40 + c], a);
        h3[c] = a;
    }
    __syncthreads();
    if (c < 64) {
        float v = -INFINITY;
        if (c < 40) v = h3[c];
        float mx = v;
#pragma unroll
        for (int off = 32; off >= 1; off >>= 1) mx = fmaxf(mx, __shfl_xor(mx, off, 64));
        float e = (c < 40) ? expf(__fsub_rn(v, mx)) : 0.f;
        float s = e;
#pragma unroll
        for (int off = 32; off >= 1; off >>= 1) s = __fadd_rn(s, __shfl_xor(s, off, 64));
        float ls = logf(s);
        if (c < 40) out[b * 40 + c] = __fsub_rn(__fsub_rn(v, mx), ls);
    }
}

// ---------------------------------------------------------------------------
extern "C" void kernel_launch(void* const* d_in, const int* in_sizes, int n_in,
                              void* d_out, int out_size, void* d_ws, size_t ws_size,
                              hipStream_t stream) {
    (void)in_sizes; (void)n_in; (void)out_size; (void)ws_size;
    const float* pos = (const float*)d_in[0];
    const float* W1a = (const float*)d_in[2];
    const float* b1a = (const float*)d_in[3];
    const float* W1b = (const float*)d_in[4];
    const float* b1b = (const float*)d_in[5];
    const float* W2a = (const float*)d_in[6];
    const float* b2a = (const float*)d_in[7];
    const float* W2b = (const float*)d_in[8];
    const float* b2b = (const float*)d_in[9];
    const float* W3a = (const float*)d_in[10];
    const float* b3a = (const float*)d_in[11];
    const float* W3b = (const float*)d_in[12];
    const float* b3b = (const float*)d_in[13];
    const float* Wl1 = (const float*)d_in[14];
    const float* bl1 = (const float*)d_in[15];
    const float* Wl2 = (const float*)d_in[16];
    const float* bl2 = (const float*)d_in[17];
    const float* Wl3 = (const float*)d_in[18];
    const float* bl3 = (const float*)d_in[19];
    float* out = (float*)d_out;

    const int B = 32;
    char* w = (char*)d_ws;
    auto alloc = [&](size_t bytes) -> char* {
        char* r = w;
        w += (bytes + 255) & ~(size_t)255;
        return r;
    };
    int*   idx1 = (int*)  alloc((size_t)B * 2048 * 33 * 4);
    float* x1   = (float*)alloc((size_t)B * 2048 * 64 * 4);
    int*   s1   = (int*)  alloc((size_t)B * 1024 * 4);
    float* pos2 = (float*)alloc((size_t)B * 1024 * 3 * 4);
    float* x2in = (float*)alloc((size_t)B * 1024 * 64 * 4);
    int*   idx2 = (int*)  alloc((size_t)B * 1024 * 33 * 4);
    float* x2   = (float*)alloc((size_t)B * 1024 * 128 * 4);
    int*   s2   = (int*)  alloc((size_t)B * 256 * 4);
    float* pos3 = (float*)alloc((size_t)B * 256 * 3 * 4);
    float* x3in = (float*)alloc((size_t)B * 256 * 128 * 4);
    int*   idx3 = (int*)  alloc((size_t)B * 256 * 33 * 4);
    float* x3   = (float*)alloc((size_t)B * 256 * 256 * 4);
    short* Wp1a = (short*)alloc(4  * 1 * 64 * 8 * 2);
    short* Wp1b = (short*)alloc(4  * 2 * 64 * 8 * 2);
    short* Wp2a = (short*)alloc(8  * 3 * 64 * 8 * 2);
    short* Wp2b = (short*)alloc(8  * 4 * 64 * 8 * 2);
    short* Wp3a = (short*)alloc(16 * 5 * 64 * 8 * 2);
    short* Wp3b = (short*)alloc(16 * 8 * 64 * 8 * 2);

    pack_w_kernel<<<1,  256, 0, stream>>>(W1a, Wp1a, 3,   64,  1, 256);
    pack_w_kernel<<<2,  256, 0, stream>>>(W1b, Wp1b, 64,  64,  2, 512);
    pack_w_kernel<<<6,  256, 0, stream>>>(W2a, Wp2a, 67,  128, 3, 1536);
    pack_w_kernel<<<8,  256, 0, stream>>>(W2b, Wp2b, 128, 128, 4, 2048);
    pack_w_kernel<<<20, 256, 0, stream>>>(W3a, Wp3a, 131, 256, 5, 5120);
    pack_w_kernel<<<32, 256, 0, stream>>>(W3b, Wp3b, 256, 256, 8, 8192);

    // ---- SA module 1 (2048 pts, r=0.2): radius + FPS fused (independent) ----
    radius_fps_kernel<2048, 1024><<<dim3(B, 513), 256, 0, stream>>>(
        pos, 0.04f, idx1, s1);
    conv_mfma_kernel<0, 64, 4, 2048><<<B * 2048 / 4, 256, 0, stream>>>(
        pos, nullptr, idx1, Wp1a, b1a, Wp1b, b1b, x1);
    gather_kernel<<<dim3(1024, B), 64, 0, stream>>>(pos, x1, s1, 2048, 1024, 64, pos2, x2in);

    // ---- SA module 2 (1024 pts, r=0.4): radius + FPS fused ----
    radius_fps_kernel<1024, 256><<<dim3(B, 257), 256, 0, stream>>>(
        pos2, 0.16f, idx2, s2);
    conv_mfma_kernel<64, 128, 1, 1024><<<B * 1024, 256, 0, stream>>>(
        pos2, x2in, idx2, Wp2a, b2a, Wp2b, b2b, x2);
    gather_kernel<<<dim3(256, B), 128, 0, stream>>>(pos2, x2, s2, 1024, 256, 128, pos3, x3in);

    // ---- SA module 3 (256 pts, r=1.0) ----
    radius_topk_kernel<256><<<dim3(B, 64), 256, 0, stream>>>(pos3, 1.0f, idx3);
    conv_mfma_kernel<128, 256, 1, 256><<<B * 256, 256, 0, stream>>>(
        pos3, x3in, idx3, Wp3a, b3a, Wp3b, b3b, x3);

    // ---- global pool + head ----
    head_kernel<<<B, 256, 0, stream>>>(x3, Wl1, bl1, Wl2, bl2, Wl3, bl3, out);
}

// Round 6
// 2239.025 us; speedup vs baseline: 4.1037x; 1.3550x over previous
//
#include <hip/hip_runtime.h>
#include <math.h>

#define DEV static __device__ __forceinline__

typedef short s8v  __attribute__((ext_vector_type(8)));   // 8 bf16 (A/B frag)
typedef short s4v  __attribute__((ext_vector_type(4)));
typedef float f4v  __attribute__((ext_vector_type(4)));   // C/D frag

// round-to-nearest-even f32 -> bf16 (bits in a short)
DEV short bf16rne(float f) {
    unsigned u = __float_as_uint(f);
    unsigned r = (u + 0x7fffu + ((u >> 16) & 1u)) >> 16;
    return (short)r;
}

// Exact-IEEE squared distance, same op order as the numpy/XLA reference.
DEV float sqd(float ax, float ay, float az, float bx, float by, float bz) {
    float dx = __fsub_rn(ax, bx), dy = __fsub_rn(ay, by), dz = __fsub_rn(az, bz);
    return __fadd_rn(__fadd_rn(__fmul_rn(dx, dx), __fmul_rn(dy, dy)), __fmul_rn(dz, dz));
}

// ---------------------------------------------------------------------------
// Fused radius top-k + FPS. blockIdx.y < N/4: radius (one wave/query).
// blockIdx.y == N/4: 256-thread FPS for the whole cloud.
//
// FPS (round-5 post-mortem redesign): coords + running d REGISTER-resident at
// only N/256 points/thread (32 VGPR — round-4's 224-reg layout spilled);
// update+argmax fused, winner COORDS carried through the reduction via
// cndmask (no post-hoc coord lookup); per-wave winner publishes key+coords to
// a double-buffered 4-slot LDS mailbox; ONE barrier per iteration (parity
// buffers make write-after-read across iterations safe). Selection math is
// exact-IEEE fp32; key = (d2_bits<<32)|~j gives argmax ties -> lowest j
// (jnp.argmax semantics).
// ---------------------------------------------------------------------------
template <int N, int M>
__global__ __launch_bounds__(256) void radius_fps_kernel(
        const float* __restrict__ pos, float rr, int* __restrict__ idx_out,
        int* __restrict__ s_out) {
    __shared__ __align__(16) unsigned long long wkey[2][4];
    __shared__ __align__(16) float wxyz[2][4][4];
    int b = blockIdx.x;
    const float* p = pos + (size_t)b * N * 3;

    if (blockIdx.y == N / 4) {
        // ---------------- FPS path: 256 threads, 1 barrier/iter ----------------
        constexpr int P = N / 256;
        int tid = threadIdx.x;
        int w = tid >> 6;
        float cx[P], cy[P], cz[P], d[P];
#pragma unroll
        for (int q = 0; q < P; q++) {
            int j = q * 256 + tid;
            cx[q] = p[j * 3 + 0];
            cy[q] = p[j * 3 + 1];
            cz[q] = p[j * 3 + 2];
            d[q] = INFINITY;
        }
        float sx = p[0], sy = p[1], sz = p[2];
        int* so = s_out + b * M;
        if (tid == 0) so[0] = 0;
#pragma unroll 1
        for (int m = 1; m < M; m++) {
            // fused d-update + argmax, winner coords tracked via cndmask
            float best = -INFINITY, bx = 0.f, by = 0.f, bz = 0.f;
            int bj = 0;
#pragma unroll
            for (int q = 0; q < P; q++) {
                float di = sqd(cx[q], cy[q], cz[q], sx, sy, sz);
                float dn = fminf(d[q], di);
                d[q] = dn;
                bool take = dn > best;     // strict >, q asc => lowest j in lane
                best = take ? dn : best;
                bj = take ? (q * 256 + tid) : bj;
                bx = take ? cx[q] : bx;
                by = take ? cy[q] : by;
                bz = take ? cz[q] : bz;
            }
            unsigned long long key =
                (((unsigned long long)__float_as_uint(best)) << 32)
                | (unsigned)(0xFFFFFFFFu - (unsigned)bj);
            unsigned long long kr = key;
#pragma unroll
            for (int off = 1; off < 64; off <<= 1) {
                unsigned long long o = __shfl_xor(kr, off, 64);
                kr = (o > kr) ? o : kr;
            }
            int par = m & 1;
            if (key == kr) {               // unique winner lane of this wave
                wkey[par][w] = kr;
                f4v cv; cv[0] = bx; cv[1] = by; cv[2] = bz; cv[3] = 0.f;
                *(f4v*)&wxyz[par][w][0] = cv;
            }
            __syncthreads();
            unsigned long long k0 = wkey[par][0], k1 = wkey[par][1];
            unsigned long long k2 = wkey[par][2], k3 = wkey[par][3];
            f4v c0 = *(const f4v*)&wxyz[par][0][0];
            f4v c1 = *(const f4v*)&wxyz[par][1][0];
            f4v c2 = *(const f4v*)&wxyz[par][2][0];
            f4v c3 = *(const f4v*)&wxyz[par][3][0];
            bool a01 = k1 > k0;
            unsigned long long k01 = a01 ? k1 : k0;
            f4v c01 = a01 ? c1 : c0;
            bool a23 = k3 > k2;
            unsigned long long k23 = a23 ? k3 : k2;
            f4v c23 = a23 ? c3 : c2;
            bool af = k23 > k01;
            unsigned long long kf = af ? k23 : k01;
            f4v cf = af ? c23 : c01;
            sx = cf[0]; sy = cf[1]; sz = cf[2];
            if (tid == 0)
                so[m] = (int)(0xFFFFFFFFu - (unsigned)(kf & 0xFFFFFFFFull));
        }
        return;
    }

    // ---------------- radius top-k path: one wave per query ----------------
    constexpr int Q = N / 64;
    constexpr unsigned long long INV = ~0ull;
    int wid = threadIdx.x >> 6, lane = threadIdx.x & 63;
    int i = blockIdx.y * 4 + wid;
    float qx = p[i * 3 + 0], qy = p[i * 3 + 1], qz = p[i * 3 + 2];

    unsigned long long c[Q];
#pragma unroll
    for (int q = 0; q < Q; q++) {
        int jj = q * 64 + lane;
        float px = p[jj * 3 + 0], py = p[jj * 3 + 1], pz = p[jj * 3 + 2];
        float d2 = sqd(px, py, pz, qx, qy, qz);
        bool valid = (jj != i) && (d2 <= rr);
        c[q] = valid ? ((((unsigned long long)__float_as_uint(d2)) << 32)
                        | (unsigned)jj)
                     : INV;
    }

#pragma unroll
    for (int k = 2; k <= Q; k <<= 1) {
#pragma unroll
        for (int jj = k >> 1; jj > 0; jj >>= 1) {
#pragma unroll
            for (int t = 0; t < Q; t++) {
                int l = t ^ jj;
                if (l > t) {
                    bool up = ((t & k) == 0);
                    unsigned long long a = c[t], d = c[l];
                    bool sw = (a > d) != up;
                    c[t] = sw ? d : a;
                    c[l] = sw ? a : d;
                }
            }
        }
    }

    int* orow = idx_out + ((size_t)b * N + i) * 33;
    int cnt = 0;
    for (int s = 0; s < 32; s++) {
        unsigned long long h = c[0];
        unsigned long long g = h;
#pragma unroll
        for (int off = 1; off < 64; off <<= 1) {
            unsigned long long o = __shfl_xor(g, off, 64);
            g = (o < g) ? o : g;
        }
        if (lane == 0) orow[s] = (int)(unsigned)(g & 0xffffffffull);
        cnt += (g != INV) ? 1 : 0;
        if (h == g && g != INV) {
#pragma unroll
            for (int q = 0; q < Q - 1; q++) c[q] = c[q + 1];
            c[Q - 1] = INV;
        }
    }
    if (lane == 0) {
        if (cnt < 32) orow[cnt] = i;
        orow[32] = (cnt == 32) ? i : -1;
    }
}

// ---------------------------------------------------------------------------
// Plain radius top-k (stage 3, no FPS needed).
// ---------------------------------------------------------------------------
template <int N>
__global__ __launch_bounds__(256) void radius_topk_kernel(
        const float* __restrict__ pos, float rr, int* __restrict__ idx_out) {
    constexpr int Q = N / 64;
    constexpr unsigned long long INV = ~0ull;
    int b = blockIdx.x;
    int wid = threadIdx.x >> 6, lane = threadIdx.x & 63;
    int i = blockIdx.y * 4 + wid;
    const float* p = pos + (size_t)b * N * 3;
    float qx = p[i * 3 + 0], qy = p[i * 3 + 1], qz = p[i * 3 + 2];

    unsigned long long c[Q];
#pragma unroll
    for (int q = 0; q < Q; q++) {
        int jj = q * 64 + lane;
        float px = p[jj * 3 + 0], py = p[jj * 3 + 1], pz = p[jj * 3 + 2];
        float d2 = sqd(px, py, pz, qx, qy, qz);
        bool valid = (jj != i) && (d2 <= rr);
        c[q] = valid ? ((((unsigned long long)__float_as_uint(d2)) << 32)
                        | (unsigned)jj)
                     : INV;
    }

#pragma unroll
    for (int k = 2; k <= Q; k <<= 1) {
#pragma unroll
        for (int jj = k >> 1; jj > 0; jj >>= 1) {
#pragma unroll
            for (int t = 0; t < Q; t++) {
                int l = t ^ jj;
                if (l > t) {
                    bool up = ((t & k) == 0);
                    unsigned long long a = c[t], d = c[l];
                    bool sw = (a > d) != up;
                    c[t] = sw ? d : a;
                    c[l] = sw ? a : d;
                }
            }
        }
    }

    int* orow = idx_out + ((size_t)b * N + i) * 33;
    int cnt = 0;
    for (int s = 0; s < 32; s++) {
        unsigned long long h = c[0];
        unsigned long long g = h;
#pragma unroll
        for (int off = 1; off < 64; off <<= 1) {
            unsigned long long o = __shfl_xor(g, off, 64);
            g = (o < g) ? o : g;
        }
        if (lane == 0) orow[s] = (int)(unsigned)(g & 0xffffffffull);
        cnt += (g != INV) ? 1 : 0;
        if (h == g && g != INV) {
#pragma unroll
            for (int q = 0; q < Q - 1; q++) c[q] = c[q + 1];
            c[Q - 1] = INV;
        }
    }
    if (lane == 0) {
        if (cnt < 32) orow[cnt] = i;
        orow[32] = (cnt == 32) ? i : -1;
    }
}

// ---------------------------------------------------------------------------
// Weight pre-pack (unchanged).
// ---------------------------------------------------------------------------
__global__ void pack_w_kernel(const float* __restrict__ W, short* __restrict__ out,
                              int Kreal, int C, int KS, int total) {
    int t = blockIdx.x * 256 + threadIdx.x;
    if (t >= total) return;
    int lane = t & 63;
    int mk = t >> 6;
    int ks = mk % KS, mt = mk / KS;
    int c = 16 * mt + (lane & 15);
    int k0 = 32 * ks + ((lane >> 4) << 3);
    s8v v;
#pragma unroll
    for (int j = 0; j < 8; j++) {
        int k = k0 + j;
        v[j] = (k < Kreal) ? bf16rne(W[(size_t)k * C + c]) : (short)0;
    }
    *(s8v*)(out + (size_t)t * 8) = v;
}

// ---------------------------------------------------------------------------
// Fused MFMA point-conv (unchanged).
// ---------------------------------------------------------------------------
template <int CXIN, int CH, int PPB, int N>
__global__ __launch_bounds__(256) void conv_mfma_kernel(
        const float* __restrict__ pos, const float* __restrict__ xin,
        const int* __restrict__ idx,
        const short* __restrict__ Wpa, const float* __restrict__ ba,
        const short* __restrict__ Wpb, const float* __restrict__ bb,
        float* __restrict__ xout) {
    constexpr int CIN  = CXIN + 3;
    constexpr int CINp = (CIN + 31) & ~31;
    constexpr int KS1  = CINp / 32, KS2 = CH / 32;
    constexpr int MT   = CH / 16;
    constexpr int MTW  = (PPB == 4) ? MT : MT / 4;
    constexpr int RP   = 48;
    constexpr int NT   = 3;
    constexpr int FS   = CINp * 2 + 16;
    constexpr int HS   = CH * 2 + 16;
    __shared__ __align__(16) char Fs[PPB * RP * FS];
    __shared__ __align__(16) char Hs[PPB * RP * HS];
    __shared__ int sj[PPB * RP];

    int tid = threadIdx.x;
    int lane = tid & 63, wid = tid >> 6;
    int pid0 = blockIdx.x * PPB;

    for (int r = tid; r < PPB * RP; r += 256) {
        int p = r / RP, s = r - p * RP;
        sj[r] = (s < 33) ? idx[(size_t)(pid0 + p) * 33 + s] : -1;
    }
    __syncthreads();

    constexpr int FE = PPB * RP * CINp;
    for (int e = tid; e < FE; e += 256) {
        int r = e / CINp, f = e - r * CINp;
        int p = r / RP;
        int pid = pid0 + p;
        int b = pid / N, i = pid - b * N;
        int j = sj[r];
        float v = 0.f;
        if (j >= 0 && f < CIN) {
            if (f < CXIN) {
                v = xin[((size_t)b * N + j) * CXIN + f];
            } else {
                int a = f - CXIN;
                v = __fsub_rn(pos[((size_t)b * N + j) * 3 + a],
                              pos[((size_t)b * N + i) * 3 + a]);
            }
        }
        *(short*)(Fs + (size_t)r * FS + f * 2) = bf16rne(v);
    }
    __syncthreads();

    int pw  = (PPB == 4) ? wid : 0;
    int mt0 = (PPB == 4) ? 0 : wid * MTW;
    const char* Fw = Fs + pw * RP * FS;
    char* Hw = Hs + pw * RP * HS;
    int lr = lane & 15, lg = lane >> 4;

    f4v acc[MTW][NT];
#pragma unroll
    for (int m = 0; m < MTW; m++)
#pragma unroll
        for (int nt = 0; nt < NT; nt++)
#pragma unroll
            for (int q = 0; q < 4; q++) acc[m][nt][q] = 0.f;
#pragma unroll
    for (int ks = 0; ks < KS1; ks++) {
        s8v bfr[NT];
#pragma unroll
        for (int nt = 0; nt < NT; nt++)
            bfr[nt] = *(const s8v*)(Fw + (nt * 16 + lr) * FS + (32 * ks + lg * 8) * 2);
#pragma unroll
        for (int m = 0; m < MTW; m++) {
            s8v afr = *(const s8v*)(Wpa + (((size_t)(mt0 + m) * KS1 + ks) * 64 + lane) * 8);
#pragma unroll
            for (int nt = 0; nt < NT; nt++)
                acc[m][nt] = __builtin_amdgcn_mfma_f32_16x16x32_bf16(afr, bfr[nt], acc[m][nt], 0, 0, 0);
        }
    }
#pragma unroll
    for (int m = 0; m < MTW; m++) {
        int cbase = (mt0 + m) * 16 + lg * 4;
        f4v bv = *(const f4v*)(ba + cbase);
#pragma unroll
        for (int nt = 0; nt < NT; nt++) {
            s4v hq;
#pragma unroll
            for (int q = 0; q < 4; q++)
                hq[q] = bf16rne(fmaxf(acc[m][nt][q] + bv[q], 0.f));
            *(s4v*)(Hw + (nt * 16 + lr) * HS + cbase * 2) = hq;
        }
    }
    __syncthreads();

    f4v acc2[MTW][NT];
#pragma unroll
    for (int m = 0; m < MTW; m++)
#pragma unroll
        for (int nt = 0; nt < NT; nt++)
#pragma unroll
            for (int q = 0; q < 4; q++) acc2[m][nt][q] = 0.f;
#pragma unroll
    for (int ks = 0; ks < KS2; ks++) {
        s8v bfr[NT];
#pragma unroll
        for (int nt = 0; nt < NT; nt++)
            bfr[nt] = *(const s8v*)(Hw + (nt * 16 + lr) * HS + (32 * ks + lg * 8) * 2);
#pragma unroll
        for (int m = 0; m < MTW; m++) {
            s8v afr = *(const s8v*)(Wpb + (((size_t)(mt0 + m) * KS2 + ks) * 64 + lane) * 8);
#pragma unroll
            for (int nt = 0; nt < NT; nt++)
                acc2[m][nt] = __builtin_amdgcn_mfma_f32_16x16x32_bf16(afr, bfr[nt], acc2[m][nt], 0, 0, 0);
        }
    }

    const int* sjw = sj + pw * RP;
#pragma unroll
    for (int m = 0; m < MTW; m++) {
        int cbase = (mt0 + m) * 16 + lg * 4;
        f4v bv = *(const f4v*)(bb + cbase);
        f4v vmx;
#pragma unroll
        for (int q = 0; q < 4; q++) vmx[q] = 0.f;
#pragma unroll
        for (int nt = 0; nt < NT; nt++) {
            int s = nt * 16 + lr;
            bool valid = (s < 33) && (sjw[s] >= 0);
#pragma unroll
            for (int q = 0; q < 4; q++) {
                float v = fmaxf(acc2[m][nt][q] + bv[q], 0.f);
                if (valid) vmx[q] = fmaxf(vmx[q], v);
            }
        }
#pragma unroll
        for (int off = 1; off < 16; off <<= 1)
#pragma unroll
            for (int q = 0; q < 4; q++)
                vmx[q] = fmaxf(vmx[q], __shfl_xor(vmx[q], off, 64));
        if (lr == 0) {
            int pid = pid0 + pw;
            *(f4v*)(xout + (size_t)pid * CH + cbase) = vmx;
        }
    }
}

// ---------------------------------------------------------------------------
__global__ void gather_kernel(
        const float* __restrict__ pos_in, const float* __restrict__ x_in,
        const int* __restrict__ s, int Nin, int M, int C,
        float* __restrict__ pos_out, float* __restrict__ x_out) {
    int b = blockIdx.y, m = blockIdx.x, t = threadIdx.x;
    int j = s[b * M + m];
    x_out[((size_t)b * M + m) * C + t] = x_in[((size_t)b * Nin + j) * C + t];
    if (t < 3) pos_out[((size_t)b * M + m) * 3 + t] = pos_in[((size_t)b * Nin + j) * 3 + t];
}

// ---------------------------------------------------------------------------
// Global max pool + MLP head + log_softmax (unchanged).
// ---------------------------------------------------------------------------
__global__ __launch_bounds__(256) void head_kernel(
        const float* __restrict__ x3,
        const float* __restrict__ Wl1, const float* __restrict__ bl1,
        const float* __restrict__ Wl2, const float* __restrict__ bl2,
        const float* __restrict__ Wl3, const float* __restrict__ bl3,
        float* __restrict__ out) {
    __shared__ float gbuf[256], h1[256], h2[256], h3[40];
    int b = blockIdx.x, c = threadIdx.x;
    const float* xb = x3 + (size_t)b * 256 * 256;
    float m = -INFINITY;
    for (int r = 0; r < 256; r++) m = fmaxf(m, xb[r * 256 + c]);
    gbuf[c] = m;
    __syncthreads();
    float a = bl1[c];
    for (int k = 0; k < 256; k++) a = fmaf(gbuf[k], Wl1[k * 256 + c], a);
    h1[c] = fmaxf(a, 0.f);
    __syncthreads();
    a = bl2[c];
    for (int k = 0; k < 256; k++) a = fmaf(h1[k], Wl2[k * 256 + c], a);
    h2[c] = fmaxf(a, 0.f);
    __syncthreads();
    if (c < 40) {
        a = bl3[c];
        for (int k = 0; k < 256; k++) a = fmaf(h2[k], Wl3[k * 40 + c], a);
        h3[c] = a;
    }
    __syncthreads();
    if (c < 64) {
        float v = -INFINITY;
        if (c < 40) v = h3[c];
        float mx = v;
#pragma unroll
        for (int off = 32; off >= 1; off >>= 1) mx = fmaxf(mx, __shfl_xor(mx, off, 64));
        float e = (c < 40) ? expf(__fsub_rn(v, mx)) : 0.f;
        float s = e;
#pragma unroll
        for (int off = 32; off >= 1; off >>= 1) s = __fadd_rn(s, __shfl_xor(s, off, 64));
        float ls = logf(s);
        if (c < 40) out[b * 40 + c] = __fsub_rn(__fsub_rn(v, mx), ls);
    }
}

// ---------------------------------------------------------------------------
extern "C" void kernel_launch(void* const* d_in, const int* in_sizes, int n_in,
                              void* d_out, int out_size, void* d_ws, size_t ws_size,
                              hipStream_t stream) {
    (void)in_sizes; (void)n_in; (void)out_size; (void)ws_size;
    const float* pos = (const float*)d_in[0];
    const float* W1a = (const float*)d_in[2];
    const float* b1a = (const float*)d_in[3];
    const float* W1b = (const float*)d_in[4];
    const float* b1b = (const float*)d_in[5];
    const float* W2a = (const float*)d_in[6];
    const float* b2a = (const float*)d_in[7];
    const float* W2b = (const float*)d_in[8];
    const float* b2b = (const float*)d_in[9];
    const float* W3a = (const float*)d_in[10];
    const float* b3a = (const float*)d_in[11];
    const float* W3b = (const float*)d_in[12];
    const float* b3b = (const float*)d_in[13];
    const float* Wl1 = (const float*)d_in[14];
    const float* bl1 = (const float*)d_in[15];
    const float* Wl2 = (const float*)d_in[16];
    const float* bl2 = (const float*)d_in[17];
    const float* Wl3 = (const float*)d_in[18];
    const float* bl3 = (const float*)d_in[19];
    float* out = (float*)d_out;

    const int B = 32;
    char* w = (char*)d_ws;
    auto alloc = [&](size_t bytes) -> char* {
        char* r = w;
        w += (bytes + 255) & ~(size_t)255;
        return r;
    };
    int*   idx1 = (int*)  alloc((size_t)B * 2048 * 33 * 4);
    float* x1   = (float*)alloc((size_t)B * 2048 * 64 * 4);
    int*   s1   = (int*)  alloc((size_t)B * 1024 * 4);
    float* pos2 = (float*)alloc((size_t)B * 1024 * 3 * 4);
    float* x2in = (float*)alloc((size_t)B * 1024 * 64 * 4);
    int*   idx2 = (int*)  alloc((size_t)B * 1024 * 33 * 4);
    float* x2   = (float*)alloc((size_t)B * 1024 * 128 * 4);
    int*   s2   = (int*)  alloc((size_t)B * 256 * 4);
    float* pos3 = (float*)alloc((size_t)B * 256 * 3 * 4);
    float* x3in = (float*)alloc((size_t)B * 256 * 128 * 4);
    int*   idx3 = (int*)  alloc((size_t)B * 256 * 33 * 4);
    float* x3   = (float*)alloc((size_t)B * 256 * 256 * 4);
    short* Wp1a = (short*)alloc(4  * 1 * 64 * 8 * 2);
    short* Wp1b = (short*)alloc(4  * 2 * 64 * 8 * 2);
    short* Wp2a = (short*)alloc(8  * 3 * 64 * 8 * 2);
    short* Wp2b = (short*)alloc(8  * 4 * 64 * 8 * 2);
    short* Wp3a = (short*)alloc(16 * 5 * 64 * 8 * 2);
    short* Wp3b = (short*)alloc(16 * 8 * 64 * 8 * 2);

    pack_w_kernel<<<1,  256, 0, stream>>>(W1a, Wp1a, 3,   64,  1, 256);
    pack_w_kernel<<<2,  256, 0, stream>>>(W1b, Wp1b, 64,  64,  2, 512);
    pack_w_kernel<<<6,  256, 0, stream>>>(W2a, Wp2a, 67,  128, 3, 1536);
    pack_w_kernel<<<8,  256, 0, stream>>>(W2b, Wp2b, 128, 128, 4, 2048);
    pack_w_kernel<<<20, 256, 0, stream>>>(W3a, Wp3a, 131, 256, 5, 5120);
    pack_w_kernel<<<32, 256, 0, stream>>>(W3b, Wp3b, 256, 256, 8, 8192);

    // ---- SA module 1 (2048 pts, r=0.2): radius + FPS fused (independent) ----
    radius_fps_kernel<2048, 1024><<<dim3(B, 513), 256, 0, stream>>>(
        pos, 0.04f, idx1, s1);
    conv_mfma_kernel<0, 64, 4, 2048><<<B * 2048 / 4, 256, 0, stream>>>(
        pos, nullptr, idx1, Wp1a, b1a, Wp1b, b1b, x1);
    gather_kernel<<<dim3(1024, B), 64, 0, stream>>>(pos, x1, s1, 2048, 1024, 64, pos2, x2in);

    // ---- SA module 2 (1024 pts, r=0.4): radius + FPS fused ----
    radius_fps_kernel<1024, 256><<<dim3(B, 257), 256, 0, stream>>>(
        pos2, 0.16f, idx2, s2);
    conv_mfma_kernel<64, 128, 1, 1024><<<B * 1024, 256, 0, stream>>>(
        pos2, x2in, idx2, Wp2a, b2a, Wp2b, b2b, x2);
    gather_kernel<<<dim3(256, B), 128, 0, stream>>>(pos2, x2, s2, 1024, 256, 128, pos3, x3in);

    // ---- SA module 3 (256 pts, r=1.0) ----
    radius_topk_kernel<256><<<dim3(B, 64), 256, 0, stream>>>(pos3, 1.0f, idx3);
    conv_mfma_kernel<128, 256, 1, 256><<<B * 256, 256, 0, stream>>>(
        pos3, x3in, idx3, Wp3a, b3a, Wp3b, b3b, x3);

    // ---- global pool + head ----
    head_kernel<<<B, 256, 0, stream>>>(x3, Wl1, bl1, Wl2, bl2, Wl3, bl3, out);
}